// Round 1
// baseline (11167.016 us; speedup 1.0000x reference)
//
#include <hip/hip_runtime.h>
#include <math.h>

#define BB   64
#define SS   512
#define DD   207
#define DINN 414
#define HH   256
#define G3   768

// ws layout (floats): WT_ih [414][768] @0 ; WT_hh [256][768] @317952 ; WT_ro [256][207] @514560
#define OFF_IH 0
#define OFF_HH 317952
#define OFF_RO 514560
#define WS_FLOATS 567552

__global__ __launch_bounds__(256) void prep_transpose(
    const float* __restrict__ W_ih, const float* __restrict__ W_hh,
    const float* __restrict__ W_ro, float* __restrict__ ws)
{
    for (int idx = blockIdx.x * blockDim.x + threadIdx.x; idx < WS_FLOATS;
         idx += gridDim.x * blockDim.x) {
        if (idx < OFF_HH) {
            int k = idx / G3, j = idx - k * G3;
            ws[idx] = W_ih[j * DINN + k];
        } else if (idx < OFF_RO) {
            int e = idx - OFF_HH;
            int k = e / G3, j = e - k * G3;
            ws[idx] = W_hh[j * HH + k];
        } else {
            int e = idx - OFF_RO;
            int k = e / DD, d = e - k * DD;
            ws[idx] = W_ro[d * HH + k];
        }
    }
}

template<bool TRANS>
__global__ __launch_bounds__(768) void rnn_kernel(
    const float* __restrict__ x, const float* __restrict__ mask,
    const float* __restrict__ W_ih, const float* __restrict__ W_hh,
    const float* __restrict__ b_ih, const float* __restrict__ b_hh,
    const float* __restrict__ W_ro, const float* __restrict__ b_ro,
    const float* __restrict__ wt,   // transposed weights in ws (valid iff TRANS)
    float* __restrict__ out)
{
    const int b   = blockIdx.x;
    const int tid = threadIdx.x;

    __shared__ __align__(16) float h[HH];
    __shared__ __align__(16) float hnew[HH];
    __shared__ __align__(16) float xin[DINN + 2];
    __shared__ __align__(16) float gi[G3];
    __shared__ __align__(16) float gh[G3];
    __shared__ __align__(16) float xhat[DD];

    // per-thread constants (tid < 768 always valid for b_ih/b_hh)
    const float bih = b_ih[tid];
    const float bhh = b_hh[tid];
    const float bro = (tid < DD) ? b_ro[tid] : 0.0f;

    if (tid < HH) h[tid] = 0.0f;
    if (tid < DD) xhat[tid] = bro;   // xhat0 = readout of h0=0 -> b_ro
    __syncthreads();

    const float* xb = x    + (size_t)b * SS * DD;
    const float* mb = mask + (size_t)b * SS * DD;
    float*       ob = out  + (size_t)b * SS * DD;

    for (int t = 0; t < SS; ++t) {
        // emit prediction for step t
        if (tid < DD) ob[t * DD + tid] = xhat[tid];
        if (t == SS - 1) break;

        // build x_in = [where(m>0.5, x, xhat), m]
        if (tid < DD) {
            float m  = mb[t * DD + tid];
            float xv = xb[t * DD + tid];
            xin[tid]      = (m > 0.5f) ? xv : xhat[tid];
            xin[DD + tid] = m;
        }
        __syncthreads();

        // GEMV: gate row `tid` of gi and gh
        float accI = bih;
        float accH = bhh;
        if (TRANS) {
            const float*  wi = wt + OFF_IH + tid;
            const float4* x4 = (const float4*)xin;
            #pragma unroll 4
            for (int k4 = 0; k4 < DINN / 4; ++k4) {
                float4 xv = x4[k4];
                int k = k4 * 4;
                accI += wi[(k + 0) * G3] * xv.x;
                accI += wi[(k + 1) * G3] * xv.y;
                accI += wi[(k + 2) * G3] * xv.z;
                accI += wi[(k + 3) * G3] * xv.w;
            }
            accI += wi[412 * G3] * xin[412];
            accI += wi[413 * G3] * xin[413];
            const float*  wh = wt + OFF_HH + tid;
            const float4* h4 = (const float4*)h;
            #pragma unroll 4
            for (int k4 = 0; k4 < HH / 4; ++k4) {
                float4 hv = h4[k4];
                int k = k4 * 4;
                accH += wh[(k + 0) * G3] * hv.x;
                accH += wh[(k + 1) * G3] * hv.y;
                accH += wh[(k + 2) * G3] * hv.z;
                accH += wh[(k + 3) * G3] * hv.w;
            }
        } else {
            const float* wi = W_ih + (size_t)tid * DINN;
            #pragma unroll 4
            for (int k = 0; k < DINN; ++k) accI += wi[k] * xin[k];
            const float* wh = W_hh + (size_t)tid * HH;
            #pragma unroll 4
            for (int k = 0; k < HH; ++k) accH += wh[k] * h[k];
        }
        gi[tid] = accI;
        gh[tid] = accH;
        __syncthreads();

        // gates: hidden unit `tid`
        if (tid < HH) {
            float r = 1.0f / (1.0f + __expf(-(gi[tid] + gh[tid])));
            float z = 1.0f / (1.0f + __expf(-(gi[HH + tid] + gh[HH + tid])));
            float n = tanhf(gi[2 * HH + tid] + r * gh[2 * HH + tid]);
            hnew[tid] = (1.0f - z) * n + z * h[tid];
        }
        __syncthreads();

        // readout: xhat = W_ro @ hnew + b_ro
        if (tid < DD) {
            float acc = bro;
            if (TRANS) {
                const float*  wr = wt + OFF_RO + tid;
                const float4* h4 = (const float4*)hnew;
                #pragma unroll 4
                for (int k4 = 0; k4 < HH / 4; ++k4) {
                    float4 hv = h4[k4];
                    int k = k4 * 4;
                    acc += wr[(k + 0) * DD] * hv.x;
                    acc += wr[(k + 1) * DD] * hv.y;
                    acc += wr[(k + 2) * DD] * hv.z;
                    acc += wr[(k + 3) * DD] * hv.w;
                }
            } else {
                const float* wr = W_ro + (size_t)tid * HH;
                #pragma unroll 4
                for (int k = 0; k < HH; ++k) acc += wr[k] * hnew[k];
            }
            xhat[tid] = acc;
        }
        if (tid < HH) h[tid] = hnew[tid];
        __syncthreads();
    }
}

extern "C" void kernel_launch(void* const* d_in, const int* in_sizes, int n_in,
                              void* d_out, int out_size, void* d_ws, size_t ws_size,
                              hipStream_t stream) {
    const float* x    = (const float*)d_in[0];
    const float* mask = (const float*)d_in[1];
    const float* W_ih = (const float*)d_in[2];
    const float* W_hh = (const float*)d_in[3];
    const float* b_ih = (const float*)d_in[4];
    const float* b_hh = (const float*)d_in[5];
    const float* W_ro = (const float*)d_in[6];
    const float* b_ro = (const float*)d_in[7];
    float* out = (float*)d_out;
    float* ws  = (float*)d_ws;

    const bool trans = (ws_size >= (size_t)WS_FLOATS * sizeof(float));
    if (trans) {
        hipLaunchKernelGGL(prep_transpose, dim3(512), dim3(256), 0, stream,
                           W_ih, W_hh, W_ro, ws);
        hipLaunchKernelGGL((rnn_kernel<true>), dim3(BB), dim3(768), 0, stream,
                           x, mask, W_ih, W_hh, b_ih, b_hh, W_ro, b_ro, ws, out);
    } else {
        hipLaunchKernelGGL((rnn_kernel<false>), dim3(BB), dim3(768), 0, stream,
                           x, mask, W_ih, W_hh, b_ih, b_hh, W_ro, b_ro, ws, out);
    }
}

// Round 2
// 10862.141 us; speedup vs baseline: 1.0281x; 1.0281x over previous
//
#include <hip/hip_runtime.h>
#include <math.h>

#define BB   64
#define SS   512
#define DD   207
#define HH   256

// ---- persistent-sharded design ----
// 64 WGs x 256 threads. WG w owns hidden units [4w,4w+4) (12 gate rows) and
// readout rows [d0,d1) (3-4 of 207). Weights LDS-resident for all steps.
// Activations exchanged via ws: actg[928][64] fp32:
//   rows 0..413   : xin (x-part 0..206, mask-part 207..413)
//   rows 414..415 : zero pad (weight cols also zeroed)
//   rows 416..671 : h parity 0
//   rows 672..927 : h parity 1
// barrier: 2 uints after actg.
#define AROWS 928
#define HBASE 416
#define ACT_FLOATS (AROWS * 64)
#define WS_NEED ((ACT_FLOATS + 2) * sizeof(float))
#define NWG 64
#define LDW 676   // padded weight row stride (672 used + 4 pad), multiple of 4

__device__ __forceinline__ void gbar(unsigned* bar, unsigned g) {
    __syncthreads();
    if (threadIdx.x == 0) {
        __builtin_amdgcn_fence(__ATOMIC_RELEASE, "agent");
        unsigned old = __hip_atomic_fetch_add(&bar[0], 1u, __ATOMIC_RELAXED,
                                              __HIP_MEMORY_SCOPE_AGENT);
        if (old == NWG - 1u) {
            __builtin_amdgcn_fence(__ATOMIC_ACQUIRE, "agent");
            __hip_atomic_store(&bar[0], 0u, __ATOMIC_RELAXED, __HIP_MEMORY_SCOPE_AGENT);
            __hip_atomic_store(&bar[1], g, __ATOMIC_RELEASE, __HIP_MEMORY_SCOPE_AGENT);
        } else {
            while (__hip_atomic_load(&bar[1], __ATOMIC_RELAXED,
                                     __HIP_MEMORY_SCOPE_AGENT) < g) { }
            __builtin_amdgcn_fence(__ATOMIC_ACQUIRE, "agent");
        }
    }
    __syncthreads();
}

// one wave computes partial dots for its k-range over 12 gate rows x 64 batches.
// lane = (u:2 | bp:4): u = hidden-unit index 0..3, bp = batch-quad 0..15.
// rows in LDS (local) are row_local = g*4+u, g in {r,z,n}.
__device__ __forceinline__ void run_range(
    const float4* __restrict__ A4, const float* __restrict__ wgl,
    float* __restrict__ red, int u, int bp, int wc0, int ar0, int len, int slot)
{
    float4 c0 = make_float4(0.f, 0.f, 0.f, 0.f);
    float4 c1 = c0, c2 = c0;
    for (int k = 0; k < len; k += 4) {
        float4 a0 = A4[(ar0 + k + 0) * 16 + bp];
        float4 a1 = A4[(ar0 + k + 1) * 16 + bp];
        float4 a2 = A4[(ar0 + k + 2) * 16 + bp];
        float4 a3 = A4[(ar0 + k + 3) * 16 + bp];
        float4 w0 = *(const float4*)&wgl[(0 + u) * LDW + wc0 + k];
        float4 w1 = *(const float4*)&wgl[(4 + u) * LDW + wc0 + k];
        float4 w2 = *(const float4*)&wgl[(8 + u) * LDW + wc0 + k];
        c0.x += a0.x*w0.x + a1.x*w0.y + a2.x*w0.z + a3.x*w0.w;
        c0.y += a0.y*w0.x + a1.y*w0.y + a2.y*w0.z + a3.y*w0.w;
        c0.z += a0.z*w0.x + a1.z*w0.y + a2.z*w0.z + a3.z*w0.w;
        c0.w += a0.w*w0.x + a1.w*w0.y + a2.w*w0.z + a3.w*w0.w;
        c1.x += a0.x*w1.x + a1.x*w1.y + a2.x*w1.z + a3.x*w1.w;
        c1.y += a0.y*w1.x + a1.y*w1.y + a2.y*w1.z + a3.y*w1.w;
        c1.z += a0.z*w1.x + a1.z*w1.y + a2.z*w1.z + a3.z*w1.w;
        c1.w += a0.w*w1.x + a1.w*w1.y + a2.w*w1.z + a3.w*w1.w;
        c2.x += a0.x*w2.x + a1.x*w2.y + a2.x*w2.z + a3.x*w2.w;
        c2.y += a0.y*w2.x + a1.y*w2.y + a2.y*w2.z + a3.y*w2.w;
        c2.z += a0.z*w2.x + a1.z*w2.y + a2.z*w2.z + a3.z*w2.w;
        c2.w += a0.w*w2.x + a1.w*w2.y + a2.w*w2.z + a3.w*w2.w;
    }
    float4* R4 = (float4*)red;
    R4[(slot * 12 + 0 + u) * 16 + bp] = c0;
    R4[(slot * 12 + 4 + u) * 16 + bp] = c1;
    R4[(slot * 12 + 8 + u) * 16 + bp] = c2;
}

__global__ __launch_bounds__(256) void rnn_init(float* __restrict__ ws) {
    int i = blockIdx.x * blockDim.x + threadIdx.x;
    const int n = (672 - 414) * 64;  // pad rows + h parity 0
    for (int idx = i; idx < n; idx += gridDim.x * blockDim.x)
        ws[414 * 64 + idx] = 0.f;
    if (i == 0) {
        unsigned* bar = (unsigned*)(ws + ACT_FLOATS);
        bar[0] = 0u; bar[1] = 0u;
    }
}

__global__ __launch_bounds__(256) void rnn_persist(
    const float* __restrict__ x, const float* __restrict__ mask,
    const float* __restrict__ W_ih, const float* __restrict__ W_hh,
    const float* __restrict__ b_ih, const float* __restrict__ b_hh,
    const float* __restrict__ W_ro, const float* __restrict__ b_ro,
    float* __restrict__ ws, float* __restrict__ out)
{
    const int wg = blockIdx.x;
    const int tid = threadIdx.x;
    const int lane = tid & 63;
    const int wv = tid >> 6;

    float* actg = ws;
    unsigned* bar = (unsigned*)(ws + ACT_FLOATS);

    __shared__ float wgl[12 * LDW];    // 12 gate rows x 676
    __shared__ float wrol[4 * 256];    // up to 4 readout rows
    __shared__ float red[5 * 12 * 64]; // gate k-partials: slots 0-2 gi, 3-4 gh
    __shared__ float redB[4 * 4 * 64]; // readout j-partials
    __shared__ float hloc[4 * 64];     // own hidden units fp32
    __shared__ float bihl[12], bhhl[12], brol[4];

    const int d0 = (207 * wg) / NWG;
    const int d1 = (207 * (wg + 1)) / NWG;
    const int dc = d1 - d0;

    // ---- startup: load owned weights into LDS ----
    for (int i = tid; i < 12 * LDW; i += 256) {
        int r = i / LDW, c = i - r * LDW;
        int rg = (r >> 2) * 256 + wg * 4 + (r & 3);  // global gate row
        float v = 0.f;
        if (c < 414) v = W_ih[rg * 414 + c];
        else if (c >= 416 && c < 672) v = W_hh[rg * 256 + (c - 416)];
        wgl[i] = v;
    }
    for (int i = tid; i < 4 * 256; i += 256) {
        int dl = i >> 8, j = i & 255;
        wrol[i] = (dl < dc) ? W_ro[(d0 + dl) * 256 + j] : 0.f;
    }
    if (tid < 12) {
        int rg = (tid >> 2) * 256 + wg * 4 + (tid & 3);
        bihl[tid] = b_ih[rg];
        bhhl[tid] = b_hh[rg];
    }
    if (tid < 4) brol[tid] = (tid < dc) ? b_ro[d0 + tid] : 0.f;
    { int u2 = tid >> 6, b = tid & 63; hloc[u2 * 64 + b] = 0.f; }
    __syncthreads();

    const float4* A4 = (const float4*)actg;
    const int u = lane >> 4;    // 0..3 (hidden unit within WG)
    const int bp = lane & 15;   // batch quad
    unsigned gen = 0;

    for (int t = 0; t < SS; ++t) {
        const int par = t & 1;
        const int hbase = HBASE + par * 256;   // rows of h_t

        // ---- Phase B: xhat_t = W_ro @ h_t + b_ro; emit out; build xin_t ----
        {
            const float* hrow = actg + hbase * 64;
            const int jb = wv * 64;
            float acc0 = 0.f, acc1 = 0.f, acc2 = 0.f, acc3 = 0.f;
            for (int j = 0; j < 64; j += 4) {
                float a0 = hrow[(jb + j + 0) * 64 + lane];
                float a1 = hrow[(jb + j + 1) * 64 + lane];
                float a2 = hrow[(jb + j + 2) * 64 + lane];
                float a3 = hrow[(jb + j + 3) * 64 + lane];
                float4 w0 = *(const float4*)&wrol[0 * 256 + jb + j];
                float4 w1 = *(const float4*)&wrol[1 * 256 + jb + j];
                float4 w2 = *(const float4*)&wrol[2 * 256 + jb + j];
                float4 w3 = *(const float4*)&wrol[3 * 256 + jb + j];
                acc0 += a0*w0.x + a1*w0.y + a2*w0.z + a3*w0.w;
                acc1 += a0*w1.x + a1*w1.y + a2*w1.z + a3*w1.w;
                acc2 += a0*w2.x + a1*w2.y + a2*w2.z + a3*w2.w;
                acc3 += a0*w3.x + a1*w3.y + a2*w3.z + a3*w3.w;
            }
            redB[(wv * 4 + 0) * 64 + lane] = acc0;
            redB[(wv * 4 + 1) * 64 + lane] = acc1;
            redB[(wv * 4 + 2) * 64 + lane] = acc2;
            redB[(wv * 4 + 3) * 64 + lane] = acc3;
        }
        __syncthreads();
        if (tid < dc * 64) {
            int dl = tid >> 6, b = tid & 63;
            float xh = redB[(0 * 4 + dl) * 64 + b] + redB[(1 * 4 + dl) * 64 + b]
                     + redB[(2 * 4 + dl) * 64 + b] + redB[(3 * 4 + dl) * 64 + b]
                     + brol[dl];
            int gidx = b * (SS * DD) + t * DD + (d0 + dl);
            out[gidx] = xh;
            if (t < SS - 1) {
                float mv = mask[gidx];
                float xv = x[gidx];
                float xi = (mv > 0.5f) ? xv : xh;
                actg[(d0 + dl) * 64 + b] = xi;          // x-part of xin
                actg[(207 + d0 + dl) * 64 + b] = mv;    // mask-part of xin
            }
        }
        if (t == SS - 1) break;

        gbar(bar, ++gen);   // xin_t and h_t published -> gates may read

        // ---- Phase A: gates -> h_{t+1} ----
        // wave k-split: wv0 xin[0,168), wv1 xin[168,336), wv2 xin[336,416)+h[0,96), wv3 h[96,256)
        if (wv == 0)      run_range(A4, wgl, red, u, bp, 0,   0,         168, 0);
        else if (wv == 1) run_range(A4, wgl, red, u, bp, 168, 168,       168, 1);
        else if (wv == 2) {
            run_range(A4, wgl, red, u, bp, 336, 336,       80,  2);
            run_range(A4, wgl, red, u, bp, 416, hbase,     96,  3);
        } else            run_range(A4, wgl, red, u, bp, 512, hbase + 96, 160, 4);
        __syncthreads();
        {
            int u2 = tid >> 6, b = tid & 63;
            float gir = red[(0*12 + 0 + u2)*64 + b] + red[(1*12 + 0 + u2)*64 + b]
                      + red[(2*12 + 0 + u2)*64 + b] + bihl[0 + u2];
            float giz = red[(0*12 + 4 + u2)*64 + b] + red[(1*12 + 4 + u2)*64 + b]
                      + red[(2*12 + 4 + u2)*64 + b] + bihl[4 + u2];
            float gin = red[(0*12 + 8 + u2)*64 + b] + red[(1*12 + 8 + u2)*64 + b]
                      + red[(2*12 + 8 + u2)*64 + b] + bihl[8 + u2];
            float ghr = red[(3*12 + 0 + u2)*64 + b] + red[(4*12 + 0 + u2)*64 + b] + bhhl[0 + u2];
            float ghz = red[(3*12 + 4 + u2)*64 + b] + red[(4*12 + 4 + u2)*64 + b] + bhhl[4 + u2];
            float ghn = red[(3*12 + 8 + u2)*64 + b] + red[(4*12 + 8 + u2)*64 + b] + bhhl[8 + u2];
            float r = 1.f / (1.f + __expf(-(gir + ghr)));
            float z = 1.f / (1.f + __expf(-(giz + ghz)));
            float n = tanhf(gin + r * ghn);
            float ho = hloc[u2 * 64 + b];
            float hn = (1.f - z) * n + z * ho;
            hloc[u2 * 64 + b] = hn;
            actg[(HBASE + (par ^ 1) * 256 + wg * 4 + u2) * 64 + b] = hn;  // publish h_{t+1}
        }
        gbar(bar, ++gen);   // h_{t+1} published -> next readout/gates may read
    }
}

// ---- fallback (round-1 style, no workspace requirement) ----
__global__ __launch_bounds__(768) void rnn_fallback(
    const float* __restrict__ x, const float* __restrict__ mask,
    const float* __restrict__ W_ih, const float* __restrict__ W_hh,
    const float* __restrict__ b_ih, const float* __restrict__ b_hh,
    const float* __restrict__ W_ro, const float* __restrict__ b_ro,
    float* __restrict__ out)
{
    const int b = blockIdx.x, tid = threadIdx.x;
    __shared__ float h[HH];
    __shared__ float hnew[HH];
    __shared__ float xin[414 + 2];
    __shared__ float gi[768];
    __shared__ float gh[768];
    __shared__ float xhat[DD];
    const float bih = b_ih[tid], bhh = b_hh[tid];
    const float bro = (tid < DD) ? b_ro[tid] : 0.f;
    if (tid < HH) h[tid] = 0.f;
    if (tid < DD) xhat[tid] = bro;
    __syncthreads();
    const float* xb = x + (size_t)b * SS * DD;
    const float* mb = mask + (size_t)b * SS * DD;
    float* ob = out + (size_t)b * SS * DD;
    for (int t = 0; t < SS; ++t) {
        if (tid < DD) ob[t * DD + tid] = xhat[tid];
        if (t == SS - 1) break;
        if (tid < DD) {
            float m = mb[t * DD + tid], xv = xb[t * DD + tid];
            xin[tid] = (m > 0.5f) ? xv : xhat[tid];
            xin[DD + tid] = m;
        }
        __syncthreads();
        float accI = bih, accH = bhh;
        const float* wi = W_ih + (size_t)tid * 414;
        for (int k = 0; k < 414; ++k) accI += wi[k] * xin[k];
        const float* wh = W_hh + (size_t)tid * HH;
        for (int k = 0; k < HH; ++k) accH += wh[k] * h[k];
        gi[tid] = accI; gh[tid] = accH;
        __syncthreads();
        if (tid < HH) {
            float r = 1.f / (1.f + __expf(-(gi[tid] + gh[tid])));
            float z = 1.f / (1.f + __expf(-(gi[HH + tid] + gh[HH + tid])));
            float n = tanhf(gi[2 * HH + tid] + r * gh[2 * HH + tid]);
            hnew[tid] = (1.f - z) * n + z * h[tid];
        }
        __syncthreads();
        if (tid < DD) {
            float acc = bro;
            const float* wr = W_ro + (size_t)tid * HH;
            for (int k = 0; k < HH; ++k) acc += wr[k] * hnew[k];
            xhat[tid] = acc;
        }
        if (tid < HH) h[tid] = hnew[tid];
        __syncthreads();
    }
}

extern "C" void kernel_launch(void* const* d_in, const int* in_sizes, int n_in,
                              void* d_out, int out_size, void* d_ws, size_t ws_size,
                              hipStream_t stream) {
    const float* x    = (const float*)d_in[0];
    const float* mask = (const float*)d_in[1];
    const float* W_ih = (const float*)d_in[2];
    const float* W_hh = (const float*)d_in[3];
    const float* b_ih = (const float*)d_in[4];
    const float* b_hh = (const float*)d_in[5];
    const float* W_ro = (const float*)d_in[6];
    const float* b_ro = (const float*)d_in[7];
    float* out = (float*)d_out;
    float* ws  = (float*)d_ws;

    if (ws_size >= WS_NEED) {
        hipLaunchKernelGGL(rnn_init, dim3(32), dim3(256), 0, stream, ws);
        hipLaunchKernelGGL(rnn_persist, dim3(NWG), dim3(256), 0, stream,
                           x, mask, W_ih, W_hh, b_ih, b_hh, W_ro, b_ro, ws, out);
    } else {
        hipLaunchKernelGGL(rnn_fallback, dim3(BB), dim3(768), 0, stream,
                           x, mask, W_ih, W_hh, b_ih, b_hh, W_ro, b_ro, out);
    }
}

// Round 3
// 8128.383 us; speedup vs baseline: 1.3738x; 1.3363x over previous
//
#include <hip/hip_runtime.h>
#include <math.h>

#define BB   64
#define SS   512
#define DD   207
#define HH   256

// ---- persistent-sharded design, v3 ----
// 64 WGs x 256 threads. WG w owns hidden units [4w,4w+4) (12 gate rows) and
// readout rows [d0,d1). Weights LDS-resident. Activations in ws actg[928][64]:
//   rows 0..413   : xin (x-part 0..206, mask-part 207..413)
//   rows 414..415 : zero pad (weight cols also zeroed)
//   rows 416..671 : h parity 0
//   rows 672..927 : h parity 1
// flags: 64 x 32 uints (128B spacing) after actg  -> all-flags barrier
// stage: [512][207][64] xhat staging (coalesced), transposed by epilogue.
#define AROWS 928
#define HBASE 416
#define ACT_FLOATS (AROWS * 64)
#define FLAG_FLOATS (64 * 32)
#define STAGE_FLOATS (SS * DD * 64)
#define WS_SMALL ((size_t)(ACT_FLOATS + FLAG_FLOATS) * sizeof(float))
#define WS_FULL  ((size_t)(ACT_FLOATS + FLAG_FLOATS + STAGE_FLOATS) * sizeof(float))
#define NWG 64
#define LDW 676   // padded weight row stride

// all-flags barrier: no central RMW. WG w stores gen into flags[w*32];
// wave-0 lane i polls flags[i*32]. Flags are monotone -> no reset race.
__device__ __forceinline__ void gbar(unsigned* flags, int wg, unsigned g) {
    __syncthreads();   // drains vmcnt -> all this-WG global stores issued
    if (threadIdx.x < 64) {
        if (threadIdx.x == 0) {
            __builtin_amdgcn_fence(__ATOMIC_RELEASE, "agent");
            __hip_atomic_store(&flags[wg * 32], g, __ATOMIC_RELAXED,
                               __HIP_MEMORY_SCOPE_AGENT);
        }
        unsigned* f = &flags[threadIdx.x * 32];
        while (__hip_atomic_load(f, __ATOMIC_RELAXED,
                                 __HIP_MEMORY_SCOPE_AGENT) < g) { }
        __builtin_amdgcn_fence(__ATOMIC_ACQUIRE, "agent");
    }
    __syncthreads();
}

__device__ __forceinline__ void run_range(
    const float4* __restrict__ A4, const float* __restrict__ wgl,
    float* __restrict__ red, int u, int bp, int wc0, int ar0, int len, int slot)
{
    float4 c0 = make_float4(0.f, 0.f, 0.f, 0.f);
    float4 c1 = c0, c2 = c0;
    for (int k = 0; k < len; k += 4) {
        float4 a0 = A4[(ar0 + k + 0) * 16 + bp];
        float4 a1 = A4[(ar0 + k + 1) * 16 + bp];
        float4 a2 = A4[(ar0 + k + 2) * 16 + bp];
        float4 a3 = A4[(ar0 + k + 3) * 16 + bp];
        float4 w0 = *(const float4*)&wgl[(0 + u) * LDW + wc0 + k];
        float4 w1 = *(const float4*)&wgl[(4 + u) * LDW + wc0 + k];
        float4 w2 = *(const float4*)&wgl[(8 + u) * LDW + wc0 + k];
        c0.x += a0.x*w0.x + a1.x*w0.y + a2.x*w0.z + a3.x*w0.w;
        c0.y += a0.y*w0.x + a1.y*w0.y + a2.y*w0.z + a3.y*w0.w;
        c0.z += a0.z*w0.x + a1.z*w0.y + a2.z*w0.z + a3.z*w0.w;
        c0.w += a0.w*w0.x + a1.w*w0.y + a2.w*w0.z + a3.w*w0.w;
        c1.x += a0.x*w1.x + a1.x*w1.y + a2.x*w1.z + a3.x*w1.w;
        c1.y += a0.y*w1.x + a1.y*w1.y + a2.y*w1.z + a3.y*w1.w;
        c1.z += a0.z*w1.x + a1.z*w1.y + a2.z*w1.z + a3.z*w1.w;
        c1.w += a0.w*w1.x + a1.w*w1.y + a2.w*w1.z + a3.w*w1.w;
        c2.x += a0.x*w2.x + a1.x*w2.y + a2.x*w2.z + a3.x*w2.w;
        c2.y += a0.y*w2.x + a1.y*w2.y + a2.y*w2.z + a3.y*w2.w;
        c2.z += a0.z*w2.x + a1.z*w2.y + a2.z*w2.z + a3.z*w2.w;
        c2.w += a0.w*w2.x + a1.w*w2.y + a2.w*w2.z + a3.w*w2.w;
    }
    float4* R4 = (float4*)red;
    R4[(slot * 12 + 0 + u) * 16 + bp] = c0;
    R4[(slot * 12 + 4 + u) * 16 + bp] = c1;
    R4[(slot * 12 + 8 + u) * 16 + bp] = c2;
}

__global__ __launch_bounds__(256) void rnn_init(float* __restrict__ ws) {
    int i = blockIdx.x * blockDim.x + threadIdx.x;
    // zero pad rows + h parity 0 (rows 414..671) and the flags
    const int nz = (672 - 414) * 64;
    for (int idx = i; idx < nz; idx += gridDim.x * blockDim.x)
        ws[414 * 64 + idx] = 0.f;
    for (int idx = i; idx < FLAG_FLOATS; idx += gridDim.x * blockDim.x)
        ((unsigned*)(ws + ACT_FLOATS))[idx] = 0u;
}

template<bool STAGE>
__global__ __launch_bounds__(256) void rnn_persist(
    const float* __restrict__ x, const float* __restrict__ mask,
    const float* __restrict__ W_ih, const float* __restrict__ W_hh,
    const float* __restrict__ b_ih, const float* __restrict__ b_hh,
    const float* __restrict__ W_ro, const float* __restrict__ b_ro,
    float* __restrict__ ws, float* __restrict__ out)
{
    const int wg = blockIdx.x;
    const int tid = threadIdx.x;
    const int lane = tid & 63;
    const int wv = tid >> 6;

    float* actg = ws;
    unsigned* flags = (unsigned*)(ws + ACT_FLOATS);
    float* stage = ws + ACT_FLOATS + FLAG_FLOATS;

    __shared__ float wgl[12 * LDW];
    __shared__ float wrol[4 * 256];
    __shared__ float red[5 * 12 * 64];
    __shared__ float redB[4 * 4 * 64];
    __shared__ float hloc[4 * 64];
    __shared__ float bihl[12], bhhl[12], brol[4];

    const int d0 = (207 * wg) / NWG;
    const int d1 = (207 * (wg + 1)) / NWG;
    const int dc = d1 - d0;

    for (int i = tid; i < 12 * LDW; i += 256) {
        int r = i / LDW, c = i - r * LDW;
        int rg = (r >> 2) * 256 + wg * 4 + (r & 3);
        float v = 0.f;
        if (c < 414) v = W_ih[rg * 414 + c];
        else if (c >= 416 && c < 672) v = W_hh[rg * 256 + (c - 416)];
        wgl[i] = v;
    }
    for (int i = tid; i < 4 * 256; i += 256) {
        int dl = i >> 8, j = i & 255;
        wrol[i] = (dl < dc) ? W_ro[(d0 + dl) * 256 + j] : 0.f;
    }
    if (tid < 12) {
        int rg = (tid >> 2) * 256 + wg * 4 + (tid & 3);
        bihl[tid] = b_ih[rg];
        bhhl[tid] = b_hh[rg];
    }
    if (tid < 4) brol[tid] = (tid < dc) ? b_ro[d0 + tid] : 0.f;
    { int u2 = tid >> 6, b = tid & 63; hloc[u2 * 64 + b] = 0.f; }
    __syncthreads();

    const float4* A4 = (const float4*)actg;
    const int u = lane >> 4;
    const int bp = lane & 15;
    unsigned gen = 0;

    // x/mask prefetch state (thread handles (dl,b) if tid < dc*64)
    const bool have = (tid < dc * 64);
    const int dl = tid >> 6, b = tid & 63;
    const size_t gbase = (size_t)b * (SS * DD) + (d0 + dl);
    float xv_pf = 0.f, mv_pf = 0.f;
    if (have) { xv_pf = x[gbase]; mv_pf = mask[gbase]; }

    for (int t = 0; t < SS; ++t) {
        const int par = t & 1;
        const int hbase = HBASE + par * 256;

        // ---- Phase B: xhat_t = W_ro @ h_t + b_ro; emit; build xin_t ----
        {
            const float* hrow = actg + hbase * 64;
            const int jb = wv * 64;
            float acc0 = 0.f, acc1 = 0.f, acc2 = 0.f, acc3 = 0.f;
            for (int j = 0; j < 64; j += 4) {
                float a0 = hrow[(jb + j + 0) * 64 + lane];
                float a1 = hrow[(jb + j + 1) * 64 + lane];
                float a2 = hrow[(jb + j + 2) * 64 + lane];
                float a3 = hrow[(jb + j + 3) * 64 + lane];
                float4 w0 = *(const float4*)&wrol[0 * 256 + jb + j];
                float4 w1 = *(const float4*)&wrol[1 * 256 + jb + j];
                float4 w2 = *(const float4*)&wrol[2 * 256 + jb + j];
                float4 w3 = *(const float4*)&wrol[3 * 256 + jb + j];
                acc0 += a0*w0.x + a1*w0.y + a2*w0.z + a3*w0.w;
                acc1 += a0*w1.x + a1*w1.y + a2*w1.z + a3*w1.w;
                acc2 += a0*w2.x + a1*w2.y + a2*w2.z + a3*w2.w;
                acc3 += a0*w3.x + a1*w3.y + a2*w3.z + a3*w3.w;
            }
            redB[(wv * 4 + 0) * 64 + lane] = acc0;
            redB[(wv * 4 + 1) * 64 + lane] = acc1;
            redB[(wv * 4 + 2) * 64 + lane] = acc2;
            redB[(wv * 4 + 3) * 64 + lane] = acc3;
        }
        __syncthreads();
        if (have) {
            float xh = redB[(0 * 4 + dl) * 64 + b] + redB[(1 * 4 + dl) * 64 + b]
                     + redB[(2 * 4 + dl) * 64 + b] + redB[(3 * 4 + dl) * 64 + b]
                     + brol[dl];
            if (STAGE) stage[(t * DD + d0 + dl) * 64 + b] = xh;   // coalesced
            else       out[gbase + (size_t)t * DD] = xh;
            if (t < SS - 1) {
                float xi = (mv_pf > 0.5f) ? xv_pf : xh;
                actg[(d0 + dl) * 64 + b] = xi;
                actg[(207 + d0 + dl) * 64 + b] = mv_pf;
            }
        }
        if (t == SS - 1) break;

        // prefetch next step's x/mask; latency hides behind barrier + gates
        if (have && t + 1 < SS - 1) {
            xv_pf = x[gbase + (size_t)(t + 1) * DD];
            mv_pf = mask[gbase + (size_t)(t + 1) * DD];
        }

        gbar(flags, wg, ++gen);   // xin_t (and h_t) published

        // ---- Phase A: gates -> h_{t+1} ----
        if (wv == 0)      run_range(A4, wgl, red, u, bp, 0,   0,          168, 0);
        else if (wv == 1) run_range(A4, wgl, red, u, bp, 168, 168,        168, 1);
        else if (wv == 2) {
            run_range(A4, wgl, red, u, bp, 336, 336,        80,  2);
            run_range(A4, wgl, red, u, bp, 416, hbase,      96,  3);
        } else            run_range(A4, wgl, red, u, bp, 512, hbase + 96, 160, 4);
        __syncthreads();
        {
            int u2 = tid >> 6, bb2 = tid & 63;
            float gir = red[(0*12 + 0 + u2)*64 + bb2] + red[(1*12 + 0 + u2)*64 + bb2]
                      + red[(2*12 + 0 + u2)*64 + bb2] + bihl[0 + u2];
            float giz = red[(0*12 + 4 + u2)*64 + bb2] + red[(1*12 + 4 + u2)*64 + bb2]
                      + red[(2*12 + 4 + u2)*64 + bb2] + bihl[4 + u2];
            float gin = red[(0*12 + 8 + u2)*64 + bb2] + red[(1*12 + 8 + u2)*64 + bb2]
                      + red[(2*12 + 8 + u2)*64 + bb2] + bihl[8 + u2];
            float ghr = red[(3*12 + 0 + u2)*64 + bb2] + red[(4*12 + 0 + u2)*64 + bb2] + bhhl[0 + u2];
            float ghz = red[(3*12 + 4 + u2)*64 + bb2] + red[(4*12 + 4 + u2)*64 + bb2] + bhhl[4 + u2];
            float ghn = red[(3*12 + 8 + u2)*64 + bb2] + red[(4*12 + 8 + u2)*64 + bb2] + bhhl[8 + u2];
            float r = 1.f / (1.f + __expf(-(gir + ghr)));
            float z = 1.f / (1.f + __expf(-(giz + ghz)));
            float n = tanhf(gin + r * ghn);
            float ho = hloc[u2 * 64 + bb2];
            float hn = (1.f - z) * n + z * ho;
            hloc[u2 * 64 + bb2] = hn;
            actg[(HBASE + (par ^ 1) * 256 + wg * 4 + u2) * 64 + bb2] = hn;
        }
        gbar(flags, wg, ++gen);   // h_{t+1} visible
    }
}

// epilogue: stage[t][d][b] -> out[b][t][d], LDS transpose, fully coalesced
__global__ __launch_bounds__(256) void out_transpose(
    const float* __restrict__ stage, float* __restrict__ out)
{
    __shared__ float lds[DD * 65];
    const int t = blockIdx.x;
    const float* st = stage + (size_t)t * DD * 64;
    for (int i = threadIdx.x; i < DD * 64; i += 256) {
        int d = i >> 6, b = i & 63;
        lds[d * 65 + b] = st[i];
    }
    __syncthreads();
    for (int i = threadIdx.x; i < DD * 64; i += 256) {
        int b = i / DD, d = i - b * DD;
        out[(size_t)b * (SS * DD) + (size_t)t * DD + d] = lds[d * 65 + b];
    }
}

// ---- fallback (round-1 style, no workspace requirement) ----
__global__ __launch_bounds__(768) void rnn_fallback(
    const float* __restrict__ x, const float* __restrict__ mask,
    const float* __restrict__ W_ih, const float* __restrict__ W_hh,
    const float* __restrict__ b_ih, const float* __restrict__ b_hh,
    const float* __restrict__ W_ro, const float* __restrict__ b_ro,
    float* __restrict__ out)
{
    const int b = blockIdx.x, tid = threadIdx.x;
    __shared__ float h[HH];
    __shared__ float hnew[HH];
    __shared__ float xin[414 + 2];
    __shared__ float gi[768];
    __shared__ float gh[768];
    __shared__ float xhat[DD];
    const float bih = b_ih[tid], bhh = b_hh[tid];
    const float bro = (tid < DD) ? b_ro[tid] : 0.f;
    if (tid < HH) h[tid] = 0.f;
    if (tid < DD) xhat[tid] = bro;
    __syncthreads();
    const float* xb = x + (size_t)b * SS * DD;
    const float* mb = mask + (size_t)b * SS * DD;
    float* ob = out + (size_t)b * SS * DD;
    for (int t = 0; t < SS; ++t) {
        if (tid < DD) ob[t * DD + tid] = xhat[tid];
        if (t == SS - 1) break;
        if (tid < DD) {
            float m = mb[t * DD + tid], xv = xb[t * DD + tid];
            xin[tid] = (m > 0.5f) ? xv : xhat[tid];
            xin[DD + tid] = m;
        }
        __syncthreads();
        float accI = bih, accH = bhh;
        const float* wi = W_ih + (size_t)tid * 414;
        for (int k = 0; k < 414; ++k) accI += wi[k] * xin[k];
        const float* wh = W_hh + (size_t)tid * HH;
        for (int k = 0; k < HH; ++k) accH += wh[k] * h[k];
        gi[tid] = accI; gh[tid] = accH;
        __syncthreads();
        if (tid < HH) {
            float r = 1.f / (1.f + __expf(-(gi[tid] + gh[tid])));
            float z = 1.f / (1.f + __expf(-(gi[HH + tid] + gh[HH + tid])));
            float n = tanhf(gi[2 * HH + tid] + r * gh[2 * HH + tid]);
            hnew[tid] = (1.f - z) * n + z * h[tid];
        }
        __syncthreads();
        if (tid < DD) {
            float acc = bro;
            const float* wr = W_ro + (size_t)tid * HH;
            for (int k = 0; k < HH; ++k) acc += wr[k] * hnew[k];
            xhat[tid] = acc;
        }
        if (tid < HH) h[tid] = hnew[tid];
        __syncthreads();
    }
}

extern "C" void kernel_launch(void* const* d_in, const int* in_sizes, int n_in,
                              void* d_out, int out_size, void* d_ws, size_t ws_size,
                              hipStream_t stream) {
    const float* x    = (const float*)d_in[0];
    const float* mask = (const float*)d_in[1];
    const float* W_ih = (const float*)d_in[2];
    const float* W_hh = (const float*)d_in[3];
    const float* b_ih = (const float*)d_in[4];
    const float* b_hh = (const float*)d_in[5];
    const float* W_ro = (const float*)d_in[6];
    const float* b_ro = (const float*)d_in[7];
    float* out = (float*)d_out;
    float* ws  = (float*)d_ws;

    if (ws_size >= WS_FULL) {
        hipLaunchKernelGGL(rnn_init, dim3(32), dim3(256), 0, stream, ws);
        hipLaunchKernelGGL((rnn_persist<true>), dim3(NWG), dim3(256), 0, stream,
                           x, mask, W_ih, W_hh, b_ih, b_hh, W_ro, b_ro, ws, out);
        hipLaunchKernelGGL(out_transpose, dim3(SS), dim3(256), 0, stream,
                           ws + ACT_FLOATS + FLAG_FLOATS, out);
    } else if (ws_size >= WS_SMALL) {
        hipLaunchKernelGGL(rnn_init, dim3(32), dim3(256), 0, stream, ws);
        hipLaunchKernelGGL((rnn_persist<false>), dim3(NWG), dim3(256), 0, stream,
                           x, mask, W_ih, W_hh, b_ih, b_hh, W_ro, b_ro, ws, out);
    } else {
        hipLaunchKernelGGL(rnn_fallback, dim3(BB), dim3(768), 0, stream,
                           x, mask, W_ih, W_hh, b_ih, b_hh, W_ro, b_ro, out);
    }
}